// Round 6
// baseline (297.606 us; speedup 1.0000x reference)
//
#include <hip/hip_runtime.h>

#define BATCH 2
#define NPT 6400
#define DD 32
#define FF 256
#define BS 128
#define NBINS 50
#define NHALF 25
#define NPTS (BATCH * NPT)   // 12800
#define NKEY 100             // keys range 0..98
#define IST 16               // i-rows per k_pairs block
#define LHW 260              // lh row stride (ushorts): 520 B, 8B-aligned rows

typedef __bf16 bf16x8 __attribute__((ext_vector_type(8)));
typedef __bf16 bf16x4 __attribute__((ext_vector_type(4)));
typedef float f32x4 __attribute__((ext_vector_type(4)));
typedef unsigned short us4 __attribute__((ext_vector_type(4)));

__device__ __forceinline__ float elu_f(float x) {
    return x > 0.0f ? x : (__expf(x) - 1.0f);
}

// ---------------- K1: LSH bin keys ----------------
__global__ void k_binkey(const float* __restrict__ xd, const float* __restrict__ cb,
                         const int* __restrict__ msk, int* __restrict__ keys) {
    int g = blockIdx.x * blockDim.x + threadIdx.x;
    if (g >= NPTS) return;
    const float4* xr4 = (const float4*)(xd + (size_t)g * DD);
    float x[DD];
#pragma unroll
    for (int q = 0; q < DD / 4; ++q) *(float4*)&x[q * 4] = xr4[q];
    float mul[NHALF];
#pragma unroll
    for (int h = 0; h < NHALF; ++h) {
        float s = 0.f;
#pragma unroll
        for (int d = 0; d < DD; ++d) s = fmaf(x[d], cb[d * 100 + h], s);
        mul[h] = s;
    }
    float best = mul[0];
    int bi = 0;
#pragma unroll
    for (int h = 1; h < NHALF; ++h)
        if (mul[h] > best) { best = mul[h]; bi = h; }
#pragma unroll
    for (int h = 0; h < NHALF; ++h) {
        float v = -mul[h];
        if (v > best) { best = v; bi = NHALF + h; }
    }
    keys[g] = bi + (msk[g] != 0 ? 0 : (NBINS - 1));
}

// ---------------- K2: stable counting sort (argsort) ----------------
// Wave-parallel column scan: wave w owns keys {4j+w}, 64 lanes x 4 cols each,
// 6-step shfl_up scan replaces the 256-iter serial LDS chain (was ~16us on
// 100/256 threads; now ~30 parallel ops/key on all 4 waves).
__global__ void k_sort(const int* __restrict__ keys, int* __restrict__ bins_i) {
    __shared__ unsigned char sk[NPT];
    __shared__ __attribute__((aligned(16))) unsigned short lh[NKEY][LHW];
    __shared__ int base[128];
    __shared__ int tot[NKEY];
    int b = blockIdx.x;
    int t = threadIdx.x;  // 0..255
    int lane = t & 63;
    int wv = t >> 6;
    for (int i = t; i < NPT; i += 256) sk[i] = (unsigned char)keys[b * NPT + i];
    // zero histogram (u64-vectorized): NKEY*LHW = 26000 ushorts = 6500 u64
    for (int i = t; i < NKEY * LHW / 4; i += 256)
        ((unsigned long long*)lh)[i] = 0ull;
    __syncthreads();
    const int CH = NPT / 256;  // 25
    int i0 = t * CH;
#pragma unroll
    for (int i = 0; i < CH; ++i) lh[sk[i0 + i]][t]++;  // column t private
    __syncthreads();
    // per-key exclusive prefix over 256 columns, wave-parallel
    for (int j = 0; j < NKEY / 4; ++j) {
        int k = j * 4 + wv;  // waves 0..3 cover keys 0..99
        us4 c = *(const us4*)&lh[k][lane * 4];
        int s = (int)c[0] + c[1] + c[2] + c[3];
        int incl = s;
#pragma unroll
        for (int off = 1; off < 64; off <<= 1) {
            int v = __shfl_up(incl, off, 64);
            if (lane >= off) incl += v;
        }
        int excl = incl - s;
        us4 o;
        o[0] = (unsigned short)excl;
        o[1] = (unsigned short)(excl + c[0]);
        o[2] = (unsigned short)(excl + c[0] + c[1]);
        o[3] = (unsigned short)(excl + c[0] + c[1] + c[2]);
        *(us4*)&lh[k][lane * 4] = o;
        if (lane == 63) tot[k] = incl;  // per-key total
    }
    __syncthreads();
    int myrun = (t < NKEY) ? tot[t] : 0;
    if (t < 128) base[t] = myrun;
    __syncthreads();
    for (int off = 1; off < 128; off <<= 1) {
        int v = (t < 128 && t >= off) ? base[t - off] : 0;
        __syncthreads();
        if (t < 128) base[t] += v;
        __syncthreads();
    }
    if (t < 128) base[t] -= myrun;  // exclusive over keys
    __syncthreads();
#pragma unroll
    for (int i = 0; i < CH; ++i) {
        int idx = i0 + i;
        int k = sk[idx];
        int pos = base[k] + lh[k][t];
        lh[k][t] = (unsigned short)(lh[k][t] + 1);
        bins_i[b * NPT + pos] = idx;
    }
}

// ---------------- K3: fused gather: features + A1/B1 + masks + bins_f ----------------
__global__ void __launch_bounds__(256) k_gather(
    const float* __restrict__ xd, const float* __restrict__ xf,
    const int* __restrict__ msk, const int* __restrict__ bins_i,
    const float* __restrict__ W1, const float* __restrict__ b1,
    float* __restrict__ out_bins, float* __restrict__ out_feat,
    float* __restrict__ a1b1, float* __restrict__ mws,
    float* __restrict__ out_msk) {
    int t = threadIdx.x;
    int wv = t >> 6;
    int l = t & 63;
    int p_lin = blockIdx.x * 4 + wv;  // 0..12799
    if (p_lin >= NPTS) return;
    int bb = p_lin / NPT;
    int idx = bins_i[p_lin];
    int src_row = bb * NPT + idx;

    // feature row copy: write-once stream -> nontemporal (ext-vector type)
    const f32x4* src = (const f32x4*)(xf + (size_t)src_row * FF);
    f32x4* dst = (f32x4*)(out_feat + (size_t)p_lin * FF);
    __builtin_nontemporal_store(src[l], &dst[l]);

    const float* xr = xd + (size_t)src_row * DD;
    int c = l & 31;
    int side = l >> 5;
    float acc = side ? b1[c] : 0.f;
    const float* Wcol = W1 + (size_t)side * DD * 32;
#pragma unroll
    for (int d = 0; d < DD; ++d) acc = fmaf(xr[d], Wcol[d * 32 + c], acc);
    a1b1[(size_t)p_lin * 64 + l] = acc;

    if (l == 0) {
        float m = (msk[src_row] != 0) ? 1.0f : 0.0f;
        mws[p_lin] = m;
        out_msk[p_lin] = m;
        out_bins[p_lin] = (float)idx;
    }
}

// ---------------- K4: pairwise FFN via MFMA ----------------
// Grid: 100 bins x 8 strips of IST=16 i-rows. Block 256 = 4 waves.
// Transposed-MFMA epilogue (2x dwordx4 stores), mask-based exact-zero skips,
// nontemporal out_dm stores (write-once 210MB stream; keep L2 for reads).
__global__ void __launch_bounds__(256) k_pairs(
    const float* __restrict__ a1b1, const float* __restrict__ mws,
    const float* __restrict__ W2, const float* __restrict__ b2,
    const float* __restrict__ W3, const float* __restrict__ b3,
    float* __restrict__ out_dm) {
    __shared__ __attribute__((aligned(16))) float B1s[128][36];
    __shared__ __attribute__((aligned(16))) float A1s[IST][36];
    __shared__ float mjs[128];
    __shared__ float mis[IST];
    __shared__ float jblk[8];   // per-16-j-block mask sum
    __shared__ float ianys;     // sum of i-row masks
    __shared__ __attribute__((aligned(16))) __bf16 scr[4][2][16 * 40];

    int t = threadIdx.x;
    int lane = t & 63;
    int wv = t >> 6;
    int n = lane & 15;
    int quad = lane >> 4;
    int koct = quad * 8;

    int bin = blockIdx.x >> 3;   // 0..99 (= b*50+bin)
    int strip = blockIdx.x & 7;  // 0..7
    int i_base = strip * IST;
    int base_p = bin * 128;

    // --- masks first: decide block-level skip before heavy staging ---
    if (t < 128) mjs[t] = mws[base_p + t];
    if (t < IST) mis[t] = mws[base_p + i_base + t];
    __syncthreads();
    if (t < 8) {
        float s = 0.f;
#pragma unroll
        for (int q = 0; q < 16; ++q) s += mjs[t * 16 + q];
        jblk[t] = s;
    }
    if (t == 8) {
        float s = 0.f;
#pragma unroll
        for (int r = 0; r < IST; ++r) s += mis[r];
        ianys = s;
    }
    __syncthreads();
    float jall = jblk[0] + jblk[1] + jblk[2] + jblk[3] +
                 jblk[4] + jblk[5] + jblk[6] + jblk[7];
    const f32x4 zz = {0.f, 0.f, 0.f, 0.f};
    if (ianys == 0.f || jall == 0.f) {
        // whole 16x128x32 block exactly zero: 256KB coalesced NT stream
        f32x4* o4 = (f32x4*)(out_dm + (size_t)(bin * 128 + i_base) * (128 * 32));
#pragma unroll 4
        for (int idx = t; idx < IST * 128 * 32 / 4; idx += 256)
            __builtin_nontemporal_store(zz, &o4[idx]);
        return;
    }

    for (int idx = t; idx < 128 * 8; idx += 256) {
        int r = idx >> 3, q = idx & 7;
        *(float4*)&B1s[r][q * 4] =
            *(const float4*)&a1b1[(size_t)(base_p + r) * 64 + 32 + q * 4];
    }
    if (t < IST * 8) {
        int r = t >> 3, q = t & 7;
        *(float4*)&A1s[r][q * 4] =
            *(const float4*)&a1b1[(size_t)(base_p + i_base + r) * 64 + q * 4];
    }

    // weight fragments (k = koct+j, col n / n+16). Used as the FIRST mfma
    // operand below => acts as Wᵀ (rows = out-cols), transposing the output.
    bf16x8 w2f0, w2f1, w3f0, w3f1;
#pragma unroll
    for (int j = 0; j < 8; ++j) {
        w2f0[j] = (__bf16)W2[(koct + j) * 32 + n];
        w2f1[j] = (__bf16)W2[(koct + j) * 32 + n + 16];
        w3f0[j] = (__bf16)W3[(koct + j) * 32 + n];
        w3f1[j] = (__bf16)W3[(koct + j) * 32 + n + 16];
    }
    // quad-indexed biases (output rows of the transposed tile)
    float4 b2lo4 = *(const float4*)&b2[quad * 4];
    float4 b2hi4 = *(const float4*)&b2[16 + quad * 4];
    float4 b3lo4 = *(const float4*)&b3[quad * 4];
    float4 b3hi4 = *(const float4*)&b3[16 + quad * 4];
    __syncthreads();  // staging barrier — the only one

    const f32x4 z = {0.f, 0.f, 0.f, 0.f};
#pragma unroll 2
    for (int g = 0; g < 32; ++g) {
        int grp = g * 4 + wv;      // 0..127
        int i_l = grp >> 3;        // 0..15
        int j0 = (grp & 7) * 16;   // 0..112

        float miv = mis[i_l];
        float jbv = jblk[grp & 7];
        size_t obase = ((size_t)(bin * 128 + i_base + i_l) * 128 + j0) * 32;

        if (miv == 0.f || jbv == 0.f) {
            // 16x32 output tile exactly zero: 2 x f32x4 per lane, coalesced
            f32x4* o4 = (f32x4*)(out_dm + obase);
            __builtin_nontemporal_store(zz, &o4[lane]);
            __builtin_nontemporal_store(zz, &o4[lane + 64]);
            continue;
        }

        float aA[8], bB[8];
        *(float4*)&aA[0] = *(float4*)&A1s[i_l][koct];
        *(float4*)&aA[4] = *(float4*)&A1s[i_l][koct + 4];
        *(float4*)&bB[0] = *(float4*)&B1s[j0 + n][koct];
        *(float4*)&bB[4] = *(float4*)&B1s[j0 + n][koct + 4];
        bf16x8 h1;  // A-frag: pair-row n, k = koct+j
#pragma unroll
        for (int j = 0; j < 8; ++j) h1[j] = (__bf16)elu_f(aA[j] + bB[j]);

        // transposed layer 2: D[hcol][pair] — lane: pair n, hcols quad*4+r (+16)
        f32x4 acc0 = __builtin_amdgcn_mfma_f32_16x16x32_bf16(w2f0, h1, z, 0, 0, 0);
        f32x4 acc1 = __builtin_amdgcn_mfma_f32_16x16x32_bf16(w2f1, h1, z, 0, 0, 0);

        // h2 -> wave-private parity scratch, 2 contiguous b64 writes
        __bf16* sc = &scr[wv][g & 1][0];
        bf16x4 h2a, h2b;
#pragma unroll
        for (int r = 0; r < 4; ++r) {
            h2a[r] = (__bf16)elu_f(acc0[r] + ((const float*)&b2lo4)[r]);
            h2b[r] = (__bf16)elu_f(acc1[r] + ((const float*)&b2hi4)[r]);
        }
        *(bf16x4*)&sc[n * 40 + quad * 4] = h2a;
        *(bf16x4*)&sc[n * 40 + 16 + quad * 4] = h2b;
        // A-frag read back: pair-row n, k = koct..koct+7
        bf16x8 h2 = *(bf16x8*)&sc[n * 40 + koct];

        // transposed layer 3: lane owns out[pair n][quad*4 .. +3] and [+16..]
        f32x4 acc2 = __builtin_amdgcn_mfma_f32_16x16x32_bf16(w3f0, h2, z, 0, 0, 0);
        f32x4 acc3 = __builtin_amdgcn_mfma_f32_16x16x32_bf16(w3f1, h2, z, 0, 0, 0);

        float mm = miv * mjs[j0 + n];
        f32x4 o0, o1;
#pragma unroll
        for (int r = 0; r < 4; ++r) {
            o0[r] = elu_f(acc2[r] + ((const float*)&b3lo4)[r]) * mm;
            o1[r] = elu_f(acc3[r] + ((const float*)&b3hi4)[r]) * mm;
        }
        __builtin_nontemporal_store(o0, (f32x4*)(out_dm + obase + (size_t)n * 32 + quad * 4));
        __builtin_nontemporal_store(o1, (f32x4*)(out_dm + obase + (size_t)n * 32 + 16 + quad * 4));
    }
}

extern "C" void kernel_launch(void* const* d_in, const int* in_sizes, int n_in,
                              void* d_out, int out_size, void* d_ws, size_t ws_size,
                              hipStream_t stream) {
    const float* xd  = (const float*)d_in[0];
    const float* xf  = (const float*)d_in[1];
    const int*   msk = (const int*)d_in[2];
    const float* cb  = (const float*)d_in[3];
    const float* W1  = (const float*)d_in[4];
    const float* b1  = (const float*)d_in[5];
    const float* W2  = (const float*)d_in[6];
    const float* b2  = (const float*)d_in[7];
    const float* W3  = (const float*)d_in[8];
    const float* b3  = (const float*)d_in[9];

    float* out = (float*)d_out;
    float* out_bins = out;                                        // 12800
    float* out_feat = out + 12800;                                // 3276800
    float* out_dm   = out + 12800 + 3276800;                      // 52428800
    float* out_msk  = out + 12800 + 3276800 + 52428800;           // 12800

    int*   keys   = (int*)d_ws;
    int*   bins_i = keys + NPTS;
    float* a1b1   = (float*)(bins_i + NPTS);
    float* mws    = a1b1 + (size_t)NPTS * 64;

    k_binkey<<<NPTS / 256, 256, 0, stream>>>(xd, cb, msk, keys);
    k_sort<<<BATCH, 256, 0, stream>>>(keys, bins_i);
    k_gather<<<NPTS / 4, 256, 0, stream>>>(xd, xf, msk, bins_i, W1, b1,
                                           out_bins, out_feat, a1b1, mws, out_msk);
    k_pairs<<<100 * 8, 256, 0, stream>>>(a1b1, mws, W2, b2, W3, b3, out_dm);
}

// Round 8
// 283.208 us; speedup vs baseline: 1.0508x; 1.0508x over previous
//
#include <hip/hip_runtime.h>

#define BATCH 2
#define NPT 6400
#define DD 32
#define FF 256
#define BS 128
#define NBINS 50
#define NHALF 25
#define NPTS (BATCH * NPT)   // 12800
#define NKEY 100             // keys range 0..98
#define IST 16               // i-rows per k_pairs block
#define LHW 260              // lh row stride (ushorts): 520 B, 8B-aligned rows

typedef __bf16 bf16x8 __attribute__((ext_vector_type(8)));
typedef __bf16 bf16x4 __attribute__((ext_vector_type(4)));
typedef float f32x4 __attribute__((ext_vector_type(4)));
typedef unsigned short us4 __attribute__((ext_vector_type(4)));

__device__ __forceinline__ float elu_f(float x) {
    return x > 0.0f ? x : (__expf(x) - 1.0f);
}

// ---------------- K1: LSH bin keys ----------------
__global__ void k_binkey(const float* __restrict__ xd, const float* __restrict__ cb,
                         const int* __restrict__ msk, int* __restrict__ keys) {
    int g = blockIdx.x * blockDim.x + threadIdx.x;
    if (g >= NPTS) return;
    const float4* xr4 = (const float4*)(xd + (size_t)g * DD);
    float x[DD];
#pragma unroll
    for (int q = 0; q < DD / 4; ++q) *(float4*)&x[q * 4] = xr4[q];
    float mul[NHALF];
#pragma unroll
    for (int h = 0; h < NHALF; ++h) {
        float s = 0.f;
#pragma unroll
        for (int d = 0; d < DD; ++d) s = fmaf(x[d], cb[d * 100 + h], s);
        mul[h] = s;
    }
    float best = mul[0];
    int bi = 0;
#pragma unroll
    for (int h = 1; h < NHALF; ++h)
        if (mul[h] > best) { best = mul[h]; bi = h; }
#pragma unroll
    for (int h = 0; h < NHALF; ++h) {
        float v = -mul[h];
        if (v > best) { best = v; bi = NHALF + h; }
    }
    keys[g] = bi + (msk[g] != 0 ? 0 : (NBINS - 1));
}

// ---------------- K2: stable counting sort (argsort) ----------------
// Wave-parallel column scan: wave w owns keys {4j+w}, 64 lanes x 4 cols each,
// 6-step shfl_up scan replaces the 256-iter serial LDS chain.
__global__ void k_sort(const int* __restrict__ keys, int* __restrict__ bins_i) {
    __shared__ unsigned char sk[NPT];
    __shared__ __attribute__((aligned(16))) unsigned short lh[NKEY][LHW];
    __shared__ int base[128];
    __shared__ int tot[NKEY];
    int b = blockIdx.x;
    int t = threadIdx.x;  // 0..255
    int lane = t & 63;
    int wv = t >> 6;
    for (int i = t; i < NPT; i += 256) sk[i] = (unsigned char)keys[b * NPT + i];
    // zero histogram (u64-vectorized): NKEY*LHW = 26000 ushorts = 6500 u64
    for (int i = t; i < NKEY * LHW / 4; i += 256)
        ((unsigned long long*)lh)[i] = 0ull;
    __syncthreads();
    const int CH = NPT / 256;  // 25
    int i0 = t * CH;
#pragma unroll
    for (int i = 0; i < CH; ++i) lh[sk[i0 + i]][t]++;  // column t private
    __syncthreads();
    // per-key exclusive prefix over 256 columns, wave-parallel
    for (int j = 0; j < NKEY / 4; ++j) {
        int k = j * 4 + wv;  // waves 0..3 cover keys 0..99
        us4 c = *(const us4*)&lh[k][lane * 4];
        int s = (int)c[0] + c[1] + c[2] + c[3];
        int incl = s;
#pragma unroll
        for (int off = 1; off < 64; off <<= 1) {
            int v = __shfl_up(incl, off, 64);
            if (lane >= off) incl += v;
        }
        int excl = incl - s;
        us4 o;
        o[0] = (unsigned short)excl;
        o[1] = (unsigned short)(excl + c[0]);
        o[2] = (unsigned short)(excl + c[0] + c[1]);
        o[3] = (unsigned short)(excl + c[0] + c[1] + c[2]);
        *(us4*)&lh[k][lane * 4] = o;
        if (lane == 63) tot[k] = incl;  // per-key total
    }
    __syncthreads();
    int myrun = (t < NKEY) ? tot[t] : 0;
    if (t < 128) base[t] = myrun;
    __syncthreads();
    for (int off = 1; off < 128; off <<= 1) {
        int v = (t < 128 && t >= off) ? base[t - off] : 0;
        __syncthreads();
        if (t < 128) base[t] += v;
        __syncthreads();
    }
    if (t < 128) base[t] -= myrun;  // exclusive over keys
    __syncthreads();
#pragma unroll
    for (int i = 0; i < CH; ++i) {
        int idx = i0 + i;
        int k = sk[idx];
        int pos = base[k] + lh[k][t];
        lh[k][t] = (unsigned short)(lh[k][t] + 1);
        bins_i[b * NPT + pos] = idx;
    }
}

// ---------------- K3: fused gather: features + A1/B1 + masks + bins_f ----------------
__global__ void __launch_bounds__(256) k_gather(
    const float* __restrict__ xd, const float* __restrict__ xf,
    const int* __restrict__ msk, const int* __restrict__ bins_i,
    const float* __restrict__ W1, const float* __restrict__ b1,
    float* __restrict__ out_bins, float* __restrict__ out_feat,
    float* __restrict__ a1b1, float* __restrict__ mws,
    float* __restrict__ out_msk) {
    int t = threadIdx.x;
    int wv = t >> 6;
    int l = t & 63;
    int p_lin = blockIdx.x * 4 + wv;  // 0..12799
    if (p_lin >= NPTS) return;
    int bb = p_lin / NPT;
    int idx = bins_i[p_lin];
    int src_row = bb * NPT + idx;

    // feature row copy: 64 lanes x float4 = 256 floats (plain stores — NT hurt)
    const float4* src = (const float4*)(xf + (size_t)src_row * FF);
    float4* dst = (float4*)(out_feat + (size_t)p_lin * FF);
    dst[l] = src[l];

    const float* xr = xd + (size_t)src_row * DD;
    int c = l & 31;
    int side = l >> 5;
    float acc = side ? b1[c] : 0.f;
    const float* Wcol = W1 + (size_t)side * DD * 32;
#pragma unroll
    for (int d = 0; d < DD; ++d) acc = fmaf(xr[d], Wcol[d * 32 + c], acc);
    a1b1[(size_t)p_lin * 64 + l] = acc;

    if (l == 0) {
        float m = (msk[src_row] != 0) ? 1.0f : 0.0f;
        mws[p_lin] = m;
        out_msk[p_lin] = m;
        out_bins[p_lin] = (float)idx;
    }
}

// ---------------- K4: pairwise FFN via MFMA ----------------
// Grid: 100 bins x 8 strips of IST=16 i-rows. Block 256 = 4 waves.
// Transposed-MFMA epilogue (2x dwordx4 stores), mask-based exact-zero skips.
// Plain stores (round-6 NT stores cost +18us: lost L2 write-buffering).
__global__ void __launch_bounds__(256) k_pairs(
    const float* __restrict__ a1b1, const float* __restrict__ mws,
    const float* __restrict__ W2, const float* __restrict__ b2,
    const float* __restrict__ W3, const float* __restrict__ b3,
    float* __restrict__ out_dm) {
    __shared__ __attribute__((aligned(16))) float B1s[128][36];
    __shared__ __attribute__((aligned(16))) float A1s[IST][36];
    __shared__ float mjs[128];
    __shared__ float mis[IST];
    __shared__ float jblk[8];   // per-16-j-block mask sum
    __shared__ float ianys;     // sum of i-row masks
    __shared__ __attribute__((aligned(16))) __bf16 scr[4][2][16 * 40];

    int t = threadIdx.x;
    int lane = t & 63;
    int wv = t >> 6;
    int n = lane & 15;
    int quad = lane >> 4;
    int koct = quad * 8;

    int bin = blockIdx.x >> 3;   // 0..99 (= b*50+bin)
    int strip = blockIdx.x & 7;  // 0..7
    int i_base = strip * IST;
    int base_p = bin * 128;

    // --- masks first: decide block-level skip before heavy staging ---
    if (t < 128) mjs[t] = mws[base_p + t];
    if (t < IST) mis[t] = mws[base_p + i_base + t];
    __syncthreads();
    if (t < 8) {
        float s = 0.f;
#pragma unroll
        for (int q = 0; q < 16; ++q) s += mjs[t * 16 + q];
        jblk[t] = s;
    }
    if (t == 8) {
        float s = 0.f;
#pragma unroll
        for (int r = 0; r < IST; ++r) s += mis[r];
        ianys = s;
    }
    __syncthreads();
    float jall = jblk[0] + jblk[1] + jblk[2] + jblk[3] +
                 jblk[4] + jblk[5] + jblk[6] + jblk[7];
    if (ianys == 0.f || jall == 0.f) {
        // whole 16x128x32 block exactly zero: 256KB coalesced stream
        const float4 zz = {0.f, 0.f, 0.f, 0.f};
        float4* o4 = (float4*)(out_dm + (size_t)(bin * 128 + i_base) * (128 * 32));
#pragma unroll 4
        for (int idx = t; idx < IST * 128 * 32 / 4; idx += 256) o4[idx] = zz;
        return;
    }

    for (int idx = t; idx < 128 * 8; idx += 256) {
        int r = idx >> 3, q = idx & 7;
        *(float4*)&B1s[r][q * 4] =
            *(const float4*)&a1b1[(size_t)(base_p + r) * 64 + 32 + q * 4];
    }
    if (t < IST * 8) {
        int r = t >> 3, q = t & 7;
        *(float4*)&A1s[r][q * 4] =
            *(const float4*)&a1b1[(size_t)(base_p + i_base + r) * 64 + q * 4];
    }

    // weight fragments (k = koct+j, col n / n+16). Used as the FIRST mfma
    // operand below => acts as Wᵀ (rows = out-cols), transposing the output.
    bf16x8 w2f0, w2f1, w3f0, w3f1;
#pragma unroll
    for (int j = 0; j < 8; ++j) {
        w2f0[j] = (__bf16)W2[(koct + j) * 32 + n];
        w2f1[j] = (__bf16)W2[(koct + j) * 32 + n + 16];
        w3f0[j] = (__bf16)W3[(koct + j) * 32 + n];
        w3f1[j] = (__bf16)W3[(koct + j) * 32 + n + 16];
    }
    // quad-indexed biases (output rows of the transposed tile)
    float4 b2lo4 = *(const float4*)&b2[quad * 4];
    float4 b2hi4 = *(const float4*)&b2[16 + quad * 4];
    float4 b3lo4 = *(const float4*)&b3[quad * 4];
    float4 b3hi4 = *(const float4*)&b3[16 + quad * 4];
    __syncthreads();  // staging barrier — the only one

    const f32x4 z = {0.f, 0.f, 0.f, 0.f};
#pragma unroll 2
    for (int g = 0; g < 32; ++g) {
        int grp = g * 4 + wv;      // 0..127
        int i_l = grp >> 3;        // 0..15
        int j0 = (grp & 7) * 16;   // 0..112

        float miv = mis[i_l];
        float jbv = jblk[grp & 7];
        size_t obase = ((size_t)(bin * 128 + i_base + i_l) * 128 + j0) * 32;

        if (miv == 0.f || jbv == 0.f) {
            // 16x32 output tile exactly zero: 2 x float4 per lane, coalesced
            const float4 zz = {0.f, 0.f, 0.f, 0.f};
            float4* o4 = (float4*)(out_dm + obase);
            o4[lane] = zz;
            o4[lane + 64] = zz;
            continue;
        }

        float aA[8], bB[8];
        *(float4*)&aA[0] = *(float4*)&A1s[i_l][koct];
        *(float4*)&aA[4] = *(float4*)&A1s[i_l][koct + 4];
        *(float4*)&bB[0] = *(float4*)&B1s[j0 + n][koct];
        *(float4*)&bB[4] = *(float4*)&B1s[j0 + n][koct + 4];
        bf16x8 h1;  // A-frag: pair-row n, k = koct+j
#pragma unroll
        for (int j = 0; j < 8; ++j) h1[j] = (__bf16)elu_f(aA[j] + bB[j]);

        // transposed layer 2: D[hcol][pair] — lane: pair n, hcols quad*4+r (+16)
        f32x4 acc0 = __builtin_amdgcn_mfma_f32_16x16x32_bf16(w2f0, h1, z, 0, 0, 0);
        f32x4 acc1 = __builtin_amdgcn_mfma_f32_16x16x32_bf16(w2f1, h1, z, 0, 0, 0);

        // h2 -> wave-private parity scratch, 2 contiguous b64 writes
        __bf16* sc = &scr[wv][g & 1][0];
        bf16x4 h2a, h2b;
#pragma unroll
        for (int r = 0; r < 4; ++r) {
            h2a[r] = (__bf16)elu_f(acc0[r] + ((const float*)&b2lo4)[r]);
            h2b[r] = (__bf16)elu_f(acc1[r] + ((const float*)&b2hi4)[r]);
        }
        *(bf16x4*)&sc[n * 40 + quad * 4] = h2a;
        *(bf16x4*)&sc[n * 40 + 16 + quad * 4] = h2b;
        // A-frag read back: pair-row n, k = koct..koct+7
        bf16x8 h2 = *(bf16x8*)&sc[n * 40 + koct];

        // transposed layer 3: lane owns out[pair n][quad*4 .. +3] and [+16..]
        f32x4 acc2 = __builtin_amdgcn_mfma_f32_16x16x32_bf16(w3f0, h2, z, 0, 0, 0);
        f32x4 acc3 = __builtin_amdgcn_mfma_f32_16x16x32_bf16(w3f1, h2, z, 0, 0, 0);

        float mm = miv * mjs[j0 + n];
        float o0[4], o1[4];
#pragma unroll
        for (int r = 0; r < 4; ++r) {
            o0[r] = elu_f(acc2[r] + ((const float*)&b3lo4)[r]) * mm;
            o1[r] = elu_f(acc3[r] + ((const float*)&b3hi4)[r]) * mm;
        }
        *(float4*)(out_dm + obase + (size_t)n * 32 + quad * 4) = *(float4*)o0;
        *(float4*)(out_dm + obase + (size_t)n * 32 + 16 + quad * 4) = *(float4*)o1;
    }
}

extern "C" void kernel_launch(void* const* d_in, const int* in_sizes, int n_in,
                              void* d_out, int out_size, void* d_ws, size_t ws_size,
                              hipStream_t stream) {
    const float* xd  = (const float*)d_in[0];
    const float* xf  = (const float*)d_in[1];
    const int*   msk = (const int*)d_in[2];
    const float* cb  = (const float*)d_in[3];
    const float* W1  = (const float*)d_in[4];
    const float* b1  = (const float*)d_in[5];
    const float* W2  = (const float*)d_in[6];
    const float* b2  = (const float*)d_in[7];
    const float* W3  = (const float*)d_in[8];
    const float* b3  = (const float*)d_in[9];

    float* out = (float*)d_out;
    float* out_bins = out;                                        // 12800
    float* out_feat = out + 12800;                                // 3276800
    float* out_dm   = out + 12800 + 3276800;                      // 52428800
    float* out_msk  = out + 12800 + 3276800 + 52428800;           // 12800

    int*   keys   = (int*)d_ws;
    int*   bins_i = keys + NPTS;
    float* a1b1   = (float*)(bins_i + NPTS);
    float* mws    = a1b1 + (size_t)NPTS * 64;

    k_binkey<<<NPTS / 256, 256, 0, stream>>>(xd, cb, msk, keys);
    k_sort<<<BATCH, 256, 0, stream>>>(keys, bins_i);
    k_gather<<<NPTS / 4, 256, 0, stream>>>(xd, xf, msk, bins_i, W1, b1,
                                           out_bins, out_feat, a1b1, mws, out_msk);
    k_pairs<<<100 * 8, 256, 0, stream>>>(a1b1, mws, W2, b2, W3, b3, out_dm);
}

// Round 9
// 275.541 us; speedup vs baseline: 1.0801x; 1.0278x over previous
//
#include <hip/hip_runtime.h>

#define BATCH 2
#define NPT 6400
#define DD 32
#define FF 256
#define BS 128
#define NBINS 50
#define NHALF 25
#define NPTS (BATCH * NPT)   // 12800
#define NKEY 100             // keys range 0..98
#define IST 8                // i-rows per k_pairs block

typedef __bf16 bf16x8 __attribute__((ext_vector_type(8)));
typedef float f32x4 __attribute__((ext_vector_type(4)));

__device__ __forceinline__ float elu_f(float x) {
    return x > 0.0f ? x : (__expf(x) - 1.0f);
}

// ---------------- K1: LSH bin keys ----------------
__global__ void k_binkey(const float* __restrict__ xd, const float* __restrict__ cb,
                         const int* __restrict__ msk, int* __restrict__ keys) {
    int g = blockIdx.x * blockDim.x + threadIdx.x;
    if (g >= NPTS) return;
    const float4* xr4 = (const float4*)(xd + (size_t)g * DD);
    float x[DD];
#pragma unroll
    for (int q = 0; q < DD / 4; ++q) *(float4*)&x[q * 4] = xr4[q];
    float mul[NHALF];
#pragma unroll
    for (int h = 0; h < NHALF; ++h) {
        float s = 0.f;
#pragma unroll
        for (int d = 0; d < DD; ++d) s = fmaf(x[d], cb[d * 100 + h], s);
        mul[h] = s;
    }
    float best = mul[0];
    int bi = 0;
#pragma unroll
    for (int h = 1; h < NHALF; ++h)
        if (mul[h] > best) { best = mul[h]; bi = h; }
#pragma unroll
    for (int h = 0; h < NHALF; ++h) {
        float v = -mul[h];
        if (v > best) { best = v; bi = NHALF + h; }
    }
    keys[g] = bi + (msk[g] != 0 ? 0 : (NBINS - 1));
}

// ---------------- K2: stable counting sort (argsort) ----------------
// bins_i only; the float copy (output 0) is emitted coalesced by k_gather.
__global__ void k_sort(const int* __restrict__ keys, int* __restrict__ bins_i) {
    __shared__ unsigned char sk[NPT];
    __shared__ unsigned short lh[NKEY][258];
    __shared__ int base[128];
    int b = blockIdx.x;
    int t = threadIdx.x;  // 0..255
    for (int i = t; i < NPT; i += 256) sk[i] = (unsigned char)keys[b * NPT + i];
    for (int k = 0; k < NKEY; ++k) lh[k][t] = 0;
    __syncthreads();
    const int CH = NPT / 256;  // 25
    int i0 = t * CH;
#pragma unroll
    for (int i = 0; i < CH; ++i) lh[sk[i0 + i]][t]++;  // column t private
    __syncthreads();
    int myrun = 0;
    if (t < NKEY) {
        int run = 0;
        for (int c = 0; c < 256; ++c) {
            int v = lh[t][c];
            lh[t][c] = (unsigned short)run;
            run += v;
        }
        myrun = run;
    }
    if (t < 128) base[t] = myrun;
    __syncthreads();
    for (int off = 1; off < 128; off <<= 1) {
        int v = (t < 128 && t >= off) ? base[t - off] : 0;
        __syncthreads();
        if (t < 128) base[t] += v;
        __syncthreads();
    }
    if (t < 128) base[t] -= myrun;  // exclusive
    __syncthreads();
#pragma unroll
    for (int i = 0; i < CH; ++i) {
        int idx = i0 + i;
        int k = sk[idx];
        int pos = base[k] + lh[k][t];
        lh[k][t] = (unsigned short)(lh[k][t] + 1);
        bins_i[b * NPT + pos] = idx;
    }
}

// ---------------- K3: fused gather: features + A1/B1 + masks + bins_f ----------------
__global__ void __launch_bounds__(256) k_gather(
    const float* __restrict__ xd, const float* __restrict__ xf,
    const int* __restrict__ msk, const int* __restrict__ bins_i,
    const float* __restrict__ W1, const float* __restrict__ b1,
    float* __restrict__ out_bins, float* __restrict__ out_feat,
    float* __restrict__ a1b1, float* __restrict__ mws,
    float* __restrict__ out_msk) {
    int t = threadIdx.x;
    int wv = t >> 6;
    int l = t & 63;
    int p_lin = blockIdx.x * 4 + wv;  // 0..12799
    if (p_lin >= NPTS) return;
    int bb = p_lin / NPT;
    int idx = bins_i[p_lin];
    int src_row = bb * NPT + idx;

    // feature row copy: 64 lanes x float4 = 256 floats
    const float4* src = (const float4*)(xf + (size_t)src_row * FF);
    float4* dst = (float4*)(out_feat + (size_t)p_lin * FF);
    dst[l] = src[l];

    // A1/B1: lane l<32 -> A col l; lane l>=32 -> B col l-32 (b1 folded)
    const float* xr = xd + (size_t)src_row * DD;
    int c = l & 31;
    int side = l >> 5;
    float acc = side ? b1[c] : 0.f;
    const float* Wcol = W1 + (size_t)side * DD * 32;
#pragma unroll
    for (int d = 0; d < DD; ++d) acc = fmaf(xr[d], Wcol[d * 32 + c], acc);
    a1b1[(size_t)p_lin * 64 + l] = acc;

    if (l == 0) {
        float m = (msk[src_row] != 0) ? 1.0f : 0.0f;
        mws[p_lin] = m;
        out_msk[p_lin] = m;
        out_bins[p_lin] = (float)idx;
    }
}

// ---------------- K4: pairwise FFN via MFMA ----------------
// Grid: 100 bins x 16 strips of IST=8 i-rows. Block 256 = 4 waves.
// Mask-based exact-zero skips at block and wave level (ref multiplies by
// m_i*m_j, so those tiles are exactly zero). Best-measured config (R1).
__global__ void __launch_bounds__(256) k_pairs(
    const float* __restrict__ a1b1, const float* __restrict__ mws,
    const float* __restrict__ W2, const float* __restrict__ b2,
    const float* __restrict__ W3, const float* __restrict__ b3,
    float* __restrict__ out_dm) {
    __shared__ __attribute__((aligned(16))) float B1s[128][36];
    __shared__ __attribute__((aligned(16))) float A1s[IST][36];
    __shared__ float mjs[128];
    __shared__ float mis[IST];
    __shared__ float jblk[8];   // per-16-j-block mask sum
    __shared__ float ianys;     // sum of i-row masks
    __shared__ __attribute__((aligned(16))) __bf16 scr[4][2][16 * 40];

    int t = threadIdx.x;
    int lane = t & 63;
    int wv = t >> 6;
    int n = lane & 15;
    int quad = lane >> 4;
    int koct = quad * 8;

    int bin = blockIdx.x >> 4;    // 0..99 (= b*50+bin)
    int strip = blockIdx.x & 15;  // 0..15
    int i_base = strip * IST;
    int base_p = bin * 128;

    // --- masks first: decide block-level skip before any heavy staging ---
    if (t < 128) mjs[t] = mws[base_p + t];
    if (t < IST) mis[t] = mws[base_p + i_base + t];
    __syncthreads();
    if (t < 8) {
        float s = 0.f;
#pragma unroll
        for (int q = 0; q < 16; ++q) s += mjs[t * 16 + q];
        jblk[t] = s;
    }
    if (t == 8) {
        float s = 0.f;
#pragma unroll
        for (int r = 0; r < IST; ++r) s += mis[r];
        ianys = s;
    }
    __syncthreads();
    float jall = jblk[0] + jblk[1] + jblk[2] + jblk[3] +
                 jblk[4] + jblk[5] + jblk[6] + jblk[7];
    if (ianys == 0.f || jall == 0.f) {
        // whole 8x128x32 block is exactly zero: 128KB coalesced stream
        const float4 zz = {0.f, 0.f, 0.f, 0.f};
        float4* o4 = (float4*)(out_dm + (size_t)(bin * 128 + i_base) * (128 * 32));
#pragma unroll 4
        for (int idx = t; idx < 8192; idx += 256) o4[idx] = zz;
        return;
    }

    for (int idx = t; idx < 128 * 8; idx += 256) {
        int r = idx >> 3, q = idx & 7;
        *(float4*)&B1s[r][q * 4] =
            *(const float4*)&a1b1[(size_t)(base_p + r) * 64 + 32 + q * 4];
    }
    if (t < IST * 8) {
        int r = t >> 3, q = t & 7;
        *(float4*)&A1s[r][q * 4] =
            *(const float4*)&a1b1[(size_t)(base_p + i_base + r) * 64 + q * 4];
    }

    // constant weight fragments (B-layout: k=koct+j, col n / n+16)
    bf16x8 w2f0, w2f1, w3f0, w3f1;
#pragma unroll
    for (int j = 0; j < 8; ++j) {
        w2f0[j] = (__bf16)W2[(koct + j) * 32 + n];
        w2f1[j] = (__bf16)W2[(koct + j) * 32 + n + 16];
        w3f0[j] = (__bf16)W3[(koct + j) * 32 + n];
        w3f1[j] = (__bf16)W3[(koct + j) * 32 + n + 16];
    }
    float b2lo = b2[n], b2hi = b2[n + 16];
    float b3lo = b3[n], b3hi = b3[n + 16];
    __syncthreads();  // staging barrier — the only one

    const f32x4 z = {0.f, 0.f, 0.f, 0.f};
#pragma unroll 2
    for (int g = 0; g < 16; ++g) {
        int grp = g * 4 + wv;      // 0..63
        int i_l = grp >> 3;
        int j0 = (grp & 7) * 16;

        float miv = mis[i_l];
        float jbv = jblk[grp & 7];
        size_t obase = ((size_t)(bin * 128 + i_base + i_l) * 128 + j0) * 32;

        if (miv == 0.f || jbv == 0.f) {
            // 16x32 output tile exactly zero: 2 x float4 per lane, coalesced
            const float4 zz = {0.f, 0.f, 0.f, 0.f};
            float4* o4 = (float4*)(out_dm + obase);
            o4[lane] = zz;
            o4[lane + 64] = zz;
            continue;
        }

        float aA[8], bB[8];
        *(float4*)&aA[0] = *(float4*)&A1s[i_l][koct];
        *(float4*)&aA[4] = *(float4*)&A1s[i_l][koct + 4];
        *(float4*)&bB[0] = *(float4*)&B1s[j0 + n][koct];
        *(float4*)&bB[4] = *(float4*)&B1s[j0 + n][koct + 4];
        bf16x8 h1;
#pragma unroll
        for (int j = 0; j < 8; ++j) h1[j] = (__bf16)elu_f(aA[j] + bB[j]);

        f32x4 acc0 = __builtin_amdgcn_mfma_f32_16x16x32_bf16(h1, w2f0, z, 0, 0, 0);
        f32x4 acc1 = __builtin_amdgcn_mfma_f32_16x16x32_bf16(h1, w2f1, z, 0, 0, 0);

        // h2 -> wave-private parity scratch in C-layout (row = quad*4+r, col)
        __bf16* sc = &scr[wv][g & 1][0];
#pragma unroll
        for (int r = 0; r < 4; ++r) {
            sc[(quad * 4 + r) * 40 + n] = (__bf16)elu_f(acc0[r] + b2lo);
            sc[(quad * 4 + r) * 40 + n + 16] = (__bf16)elu_f(acc1[r] + b2hi);
        }
        // A-layout read back: row m = n (pair), k = koct..koct+7
        bf16x8 h2 = *(bf16x8*)&sc[n * 40 + koct];
        f32x4 acc2 = __builtin_amdgcn_mfma_f32_16x16x32_bf16(h2, w3f0, z, 0, 0, 0);
        f32x4 acc3 = __builtin_amdgcn_mfma_f32_16x16x32_bf16(h2, w3f1, z, 0, 0, 0);

        size_t obase2 = obase;
#pragma unroll
        for (int r = 0; r < 4; ++r) {
            int jr = quad * 4 + r;
            float mm = miv * mjs[j0 + jr];
            out_dm[obase2 + (size_t)jr * 32 + n] = elu_f(acc2[r] + b3lo) * mm;
            out_dm[obase2 + (size_t)jr * 32 + n + 16] = elu_f(acc3[r] + b3hi) * mm;
        }
    }
}

extern "C" void kernel_launch(void* const* d_in, const int* in_sizes, int n_in,
                              void* d_out, int out_size, void* d_ws, size_t ws_size,
                              hipStream_t stream) {
    const float* xd  = (const float*)d_in[0];
    const float* xf  = (const float*)d_in[1];
    const int*   msk = (const int*)d_in[2];
    const float* cb  = (const float*)d_in[3];
    const float* W1  = (const float*)d_in[4];
    const float* b1  = (const float*)d_in[5];
    const float* W2  = (const float*)d_in[6];
    const float* b2  = (const float*)d_in[7];
    const float* W3  = (const float*)d_in[8];
    const float* b3  = (const float*)d_in[9];

    float* out = (float*)d_out;
    float* out_bins = out;                                        // 12800
    float* out_feat = out + 12800;                                // 3276800
    float* out_dm   = out + 12800 + 3276800;                      // 52428800
    float* out_msk  = out + 12800 + 3276800 + 52428800;           // 12800

    int*   keys   = (int*)d_ws;
    int*   bins_i = keys + NPTS;
    float* a1b1   = (float*)(bins_i + NPTS);
    float* mws    = a1b1 + (size_t)NPTS * 64;

    k_binkey<<<NPTS / 256, 256, 0, stream>>>(xd, cb, msk, keys);
    k_sort<<<BATCH, 256, 0, stream>>>(keys, bins_i);
    k_gather<<<NPTS / 4, 256, 0, stream>>>(xd, xf, msk, bins_i, W1, b1,
                                           out_bins, out_feat, a1b1, mws, out_msk);
    k_pairs<<<100 * 16, 256, 0, stream>>>(a1b1, mws, W2, b2, W3, b3, out_dm);
}